// Round 1
// baseline (2942.021 us; speedup 1.0000x reference)
//
#include <hip/hip_runtime.h>
#include <math.h>

#define IN_DIM 300
#define MEM 256
#define DEPTH 15
#define NNODES ((1 << (DEPTH + 1)) - 1)   // 65535

// ws layout (floats):
//   wtx [IN_DIM][1024] : cols 0..767 = W_ioux^T, cols 768..1023 = W_fx^T   (307200)
//   wth [MEM][1024]    : cols 0..767 = W_iouh^T, cols 768..1023 = W_fh^T   (262144)
#define WTX_ELEMS (IN_DIM * 1024)
#define WTH_ELEMS (MEM * 1024)

__device__ __forceinline__ float sigmoidf_(float x) {
    return 1.0f / (1.0f + __expf(-x));
}
__device__ __forceinline__ float tanhfast_(float x) {
    // stable at large |x|: exp overflow -> +inf -> 1; exp underflow -> 0 -> -1
    return 1.0f - 2.0f / (__expf(2.0f * x) + 1.0f);
}

__global__ void transpose_weights(const float* __restrict__ W_ioux,
                                  const float* __restrict__ W_fx,
                                  const float* __restrict__ W_iouh,
                                  const float* __restrict__ W_fh,
                                  float* __restrict__ ws) {
    int tid = blockIdx.x * blockDim.x + threadIdx.x;
    if (tid < WTX_ELEMS) {
        int k = tid >> 10, col = tid & 1023;
        float v = (col < 768) ? W_ioux[col * IN_DIM + k]
                              : W_fx[(col - 768) * IN_DIM + k];
        ws[tid] = v;
    } else if (tid < WTX_ELEMS + WTH_ELEMS) {
        int t = tid - WTX_ELEMS;
        int k = t >> 10, col = t & 1023;
        float v = (col < 768) ? W_iouh[col * MEM + k]
                              : W_fh[(col - 768) * MEM + k];
        ws[WTX_ELEMS + t] = v;
    }
}

// One block = 16 consecutive nodes of a level. 256 threads; thread j owns
// output column j of each 256-wide group (i / o / u / f-related).
template <bool LEAF>
__global__ __launch_bounds__(256, 2) void level_kernel(
    const float* __restrict__ x_in,   // inputs [N, IN_DIM]
    const float* __restrict__ wtx,    // [IN_DIM][1024]
    const float* __restrict__ wth,    // [MEM][1024]
    const float* __restrict__ b_ioux, // [768]
    const float* __restrict__ b_iouh, // [768]
    const float* __restrict__ b_fx,   // [256]
    const float* __restrict__ b_fh,   // [256]
    float* __restrict__ c,            // [N, MEM] (= d_out)
    float* __restrict__ h,            // [N, MEM] (= d_out + N*MEM)
    int start, int levsize)
{
    const int j = threadIdx.x;            // 0..255  (output column)
    const int tile0 = blockIdx.x * 16;    // node offset within level
    const int mcount = min(16, levsize - tile0);

    __shared__ __align__(16) float Xs[16 * IN_DIM];                  // 19.2 KB
    __shared__ __align__(16) float Hs[LEAF ? 16 : 32 * MEM];         // 32 KB (internal)

    // ---- stage X tile (nodes are consecutive rows -> fully contiguous) ----
    {
        const float4* g4 = (const float4*)(x_in + (size_t)(start + tile0) * IN_DIM);
        float4* s4 = (float4*)Xs;
        const int nvec = mcount * (IN_DIM / 4);          // IN_DIM%4==0
        for (int t = j; t < 16 * (IN_DIM / 4); t += 256) {
            float4 v = make_float4(0.f, 0.f, 0.f, 0.f);
            if (t < nvec) v = g4[t];
            s4[t] = v;
        }
    }
    // ---- stage children H tile: rows [childbase, childbase+2*mcount) contiguous ----
    int childbase = 0;
    if constexpr (!LEAF) {
        childbase = 2 * (start + tile0) + 1;
        const float4* g4 = (const float4*)(h + (size_t)childbase * MEM);
        float4* s4 = (float4*)Hs;
        const int nvec = 2 * mcount * (MEM / 4);
        for (int t = j; t < 32 * (MEM / 4); t += 256) {
            float4 v = make_float4(0.f, 0.f, 0.f, 0.f);
            if (t < nvec) v = g4[t];
            s4[t] = v;
        }
    }
    __syncthreads();

    constexpr int NGA = LEAF ? 3 : 4;     // leaves: skip fx column group
    float accA[NGA][16];
#pragma unroll
    for (int g = 0; g < NGA; ++g)
#pragma unroll
        for (int m = 0; m < 16; ++m) accA[g][m] = 0.f;

    // ---- Phase A: X[16][300] @ WTX[300][NGA*256] ----
    for (int k4 = 0; k4 < IN_DIM; k4 += 4) {
        float wv[4][NGA];
#pragma unroll
        for (int kk = 0; kk < 4; ++kk)
#pragma unroll
            for (int g = 0; g < NGA; ++g)
                wv[kk][g] = wtx[(k4 + kk) * 1024 + g * 256 + j];
#pragma unroll
        for (int m = 0; m < 16; ++m) {
            float4 xv = *(const float4*)&Xs[m * IN_DIM + k4];
#pragma unroll
            for (int g = 0; g < NGA; ++g) {
                accA[g][m] += xv.x * wv[0][g];
                accA[g][m] += xv.y * wv[1][g];
                accA[g][m] += xv.z * wv[2][g];
                accA[g][m] += xv.w * wv[3][g];
            }
        }
    }

    // ---- Phase B (internal only): hsum @ W_iouh^T, hl/hr @ W_fh^T ----
    float accFL[16], accFR[16];
    if constexpr (!LEAF) {
#pragma unroll
        for (int m = 0; m < 16; ++m) { accFL[m] = 0.f; accFR[m] = 0.f; }
        for (int k4 = 0; k4 < MEM; k4 += 4) {
            float wv[4][4];
#pragma unroll
            for (int kk = 0; kk < 4; ++kk)
#pragma unroll
                for (int g = 0; g < 4; ++g)
                    wv[kk][g] = wth[(k4 + kk) * 1024 + g * 256 + j];
#pragma unroll
            for (int m = 0; m < 16; ++m) {
                float4 hl = *(const float4*)&Hs[(2 * m) * MEM + k4];
                float4 hr = *(const float4*)&Hs[(2 * m + 1) * MEM + k4];
                float hsx = hl.x + hr.x, hsy = hl.y + hr.y;
                float hsz = hl.z + hr.z, hsw = hl.w + hr.w;
#pragma unroll
                for (int g = 0; g < 3; ++g) {
                    accA[g][m] += hsx * wv[0][g] + hsy * wv[1][g]
                                + hsz * wv[2][g] + hsw * wv[3][g];
                }
                accFL[m] += hl.x * wv[0][3] + hl.y * wv[1][3]
                          + hl.z * wv[2][3] + hl.w * wv[3][3];
                accFR[m] += hr.x * wv[0][3] + hr.y * wv[1][3]
                          + hr.z * wv[2][3] + hr.w * wv[3][3];
            }
        }
    }

    // ---- epilogue: biases, gates, c/h store (coalesced: thread j = col j) ----
    const float bi = b_ioux[j]       + b_iouh[j];
    const float bo = b_ioux[256 + j] + b_iouh[256 + j];
    const float bu = b_ioux[512 + j] + b_iouh[512 + j];
    float bfv = 0.f, bfxv = 0.f;
    if constexpr (!LEAF) { bfv = b_fh[j]; bfxv = b_fx[j]; }

#pragma unroll
    for (int m = 0; m < 16; ++m) {
        if (m < mcount) {
            float iv = sigmoidf_(accA[0][m] + bi);
            float ov = sigmoidf_(accA[1][m] + bo);
            float uv = tanhfast_(accA[2][m] + bu);
            float cn;
            if constexpr (!LEAF) {
                float fxv = accA[3][m] + bfxv;
                float fl = sigmoidf_(accFL[m] + bfv + fxv);
                float fr = sigmoidf_(accFR[m] + bfv + fxv);
                float clv = c[(size_t)(childbase + 2 * m) * MEM + j];
                float crv = c[(size_t)(childbase + 2 * m + 1) * MEM + j];
                cn = iv * uv + fl * clv + fr * crv;
            } else {
                cn = iv * uv;
            }
            float hn = ov * tanhfast_(cn);
            size_t node = (size_t)(start + tile0 + m);
            c[node * MEM + j] = cn;
            h[node * MEM + j] = hn;
        }
    }
}

extern "C" void kernel_launch(void* const* d_in, const int* in_sizes, int n_in,
                              void* d_out, int out_size, void* d_ws, size_t ws_size,
                              hipStream_t stream) {
    const float* inputs = (const float*)d_in[0];
    const float* W_ioux = (const float*)d_in[1];
    const float* b_ioux = (const float*)d_in[2];
    const float* W_iouh = (const float*)d_in[3];
    const float* b_iouh = (const float*)d_in[4];
    const float* W_fx   = (const float*)d_in[5];
    const float* b_fx   = (const float*)d_in[6];
    const float* W_fh   = (const float*)d_in[7];
    const float* b_fh   = (const float*)d_in[8];

    float* out = (float*)d_out;
    float* c = out;                                  // [N, MEM]
    float* h = out + (size_t)NNODES * MEM;           // [N, MEM]

    float* ws  = (float*)d_ws;
    float* wtx = ws;                                 // [300][1024]
    float* wth = ws + WTX_ELEMS;                     // [256][1024]

    {
        int total = WTX_ELEMS + WTH_ELEMS;
        hipLaunchKernelGGL(transpose_weights, dim3((total + 255) / 256), dim3(256),
                           0, stream, W_ioux, W_fx, W_iouh, W_fh, ws);
    }

    for (int d = DEPTH; d >= 0; --d) {
        int start = (1 << d) - 1;
        int sz = 1 << d;
        int blocks = (sz + 15) / 16;
        if (d == DEPTH) {
            hipLaunchKernelGGL((level_kernel<true>), dim3(blocks), dim3(256), 0, stream,
                               inputs, wtx, wth, b_ioux, b_iouh, b_fx, b_fh,
                               c, h, start, sz);
        } else {
            hipLaunchKernelGGL((level_kernel<false>), dim3(blocks), dim3(256), 0, stream,
                               inputs, wtx, wth, b_ioux, b_iouh, b_fx, b_fh,
                               c, h, start, sz);
        }
    }
}

// Round 2
// 1051.695 us; speedup vs baseline: 2.7974x; 2.7974x over previous
//
#include <hip/hip_runtime.h>
#include <math.h>

#define IN_DIM 300
#define MEM 256
#define DEPTH 15
#define NNODES ((1 << (DEPTH + 1)) - 1)   // 65535
#define KX 320    // K for x-GEMM (300 zero-padded to mult of 32)
#define KH 256    // K for h-GEMM
#define SX 328    // LDS row stride (bf16) for X tile  (328*2B: 16B-aligned, banks spread)
#define SH 264    // LDS row stride (bf16) for H tiles

typedef __attribute__((ext_vector_type(8))) __bf16 bf16x8;
typedef __attribute__((ext_vector_type(4))) float f32x4;

__device__ __forceinline__ float sigmoidf_(float x) { return 1.0f / (1.0f + __expf(-x)); }
__device__ __forceinline__ float tanhfast_(float x) {
    // stable: exp overflow -> +inf -> 1; underflow -> 0 -> -1
    return 1.0f - 2.0f / (__expf(2.0f * x) + 1.0f);
}

__device__ __forceinline__ f32x4 mfma_bf16(bf16x8 a, bf16x8 b, f32x4 acc) {
    return __builtin_amdgcn_mfma_f32_16x16x32_bf16(a, b, acc, 0, 0, 0);
}

// ws layout (bf16):
//   wtx [1024][KX]: rows 0..767 = W_ioux (i,o,u), rows 768..1023 = W_fx; cols 300..319 zero
//   wth [1024][KH]: rows 0..767 = W_iouh,         rows 768..1023 = W_fh
// Row-major [out_col][k] is exactly the MFMA B-fragment layout (lane reads 8
// consecutive k for its column) -> no transpose, direct 16B global loads.
#define WTX_ELEMS (1024 * KX)
#define WTH_ELEMS (1024 * KH)

__global__ void prep_weights(const float* __restrict__ W_ioux, const float* __restrict__ W_fx,
                             const float* __restrict__ W_iouh, const float* __restrict__ W_fh,
                             __bf16* __restrict__ ws) {
    int idx = blockIdx.x * 256 + threadIdx.x;
    if (idx < WTX_ELEMS) {
        int n = idx / KX, k = idx % KX;
        float v = 0.f;
        if (k < IN_DIM) v = (n < 768) ? W_ioux[n * IN_DIM + k] : W_fx[(n - 768) * IN_DIM + k];
        ws[idx] = (__bf16)v;
    } else if (idx < WTX_ELEMS + WTH_ELEMS) {
        int t = idx - WTX_ELEMS;
        int n = t / KH, k = t % KH;
        float v = (n < 768) ? W_iouh[n * MEM + k] : W_fh[(n - 768) * MEM + k];
        ws[WTX_ELEMS + t] = (__bf16)v;
    }
}

// One block = 16 nodes of a level. 1024 threads = 16 waves.
// Wave w owns output columns [16w, 16w+16) of ALL four 256-col groups, so the
// gate epilogue is wave-local (tiny 16x16 LDS exchange, no cross-wave traffic).
template <bool LEAF>
__global__ __launch_bounds__(1024, 4) void level_mfma(
    const float* __restrict__ x_in,
    const __bf16* __restrict__ wtx,
    const __bf16* __restrict__ wth,
    const float* __restrict__ b_ioux, const float* __restrict__ b_iouh,
    const float* __restrict__ b_fx, const float* __restrict__ b_fh,
    float* __restrict__ c, float* __restrict__ h,
    int start, int levsize)
{
    const int tid = threadIdx.x;
    const int w = tid >> 6;        // wave 0..15
    const int l = tid & 63;
    const int lc = l & 15;         // col-in-tile / A-row lane
    const int q = l >> 4;          // quad
    const int tile0 = blockIdx.x * 16;
    const int node0 = start + tile0;
    const int mcount = min(16, levsize - tile0);
    const int childbase = 2 * node0 + 1;

    __shared__ __align__(16) __bf16 Xs[16 * SX];                    // 10.25 KB
    __shared__ __align__(16) __bf16 Hsum[LEAF ? 8 : 16 * SH];       // 8.25 KB
    __shared__ __align__(16) __bf16 Hlr[LEAF ? 8 : 32 * SH];        // 16.5 KB
    __shared__ float Scr[LEAF ? 1 : 16][272];                       // 17 KB (per-wave 16x17)

    // ---- stage X tile -> bf16 LDS (zero-pad k>=300 and rows >= mcount) ----
    for (int t = tid; t < 16 * KX; t += 1024) {
        int m = t / KX, k = t - m * KX;
        float v = (m < mcount && k < IN_DIM) ? x_in[(size_t)(node0 + m) * IN_DIM + k] : 0.f;
        Xs[m * SX + k] = (__bf16)v;
    }
    // ---- stage children h: Hlr rows 2m,2m+1 and Hsum = hl+hr (fp32 add) ----
    if constexpr (!LEAF) {
        for (int t = tid; t < 16 * KH; t += 1024) {
            int m = t >> 8, k = t & 255;
            float hl = 0.f, hr = 0.f;
            if (m < mcount) {
                hl = h[(size_t)(childbase + 2 * m) * MEM + k];
                hr = h[(size_t)(childbase + 2 * m + 1) * MEM + k];
            }
            Hlr[(2 * m) * SH + k] = (__bf16)hl;
            Hlr[(2 * m + 1) * SH + k] = (__bf16)hr;
            Hsum[m * SH + k] = (__bf16)(hl + hr);
        }
    }
    __syncthreads();

    constexpr int NG1 = LEAF ? 3 : 4;      // leaves don't need the fx group
    const f32x4 z4 = {0.f, 0.f, 0.f, 0.f};
    f32x4 accG1[NG1];
    f32x4 accG2a[3], accG2b[2];
#pragma unroll
    for (int t = 0; t < NG1; ++t) accG1[t] = z4;
#pragma unroll
    for (int t = 0; t < 3; ++t) accG2a[t] = z4;
    accG2b[0] = z4; accG2b[1] = z4;

    const int colw = (w << 4) | lc;        // output col 0..255 (within each group)
    const int koff = q << 3;               // A/B fragment k-offset = 8*quad

    // ---- GEMM2: h-path (K=256, 8 k-steps) ----
    if constexpr (!LEAF) {
        const __bf16* aS = &Hsum[lc * SH + koff];
        const __bf16* aL = &Hlr[lc * SH + koff];
        const __bf16* aR = &Hlr[(16 + lc) * SH + koff];
        const __bf16* bI = wth + (size_t)colw * KH + koff;
        const __bf16* bF = wth + (size_t)(768 + colw) * KH + koff;
#pragma unroll
        for (int ks = 0; ks < KH / 32; ++ks) {
            bf16x8 a2 = *(const bf16x8*)(aS + 32 * ks);
            bf16x8 al = *(const bf16x8*)(aL + 32 * ks);
            bf16x8 ar = *(const bf16x8*)(aR + 32 * ks);
            accG2a[0] = mfma_bf16(a2, *(const bf16x8*)(bI + 32 * ks), accG2a[0]);
            accG2a[1] = mfma_bf16(a2, *(const bf16x8*)(bI + (size_t)256 * KH + 32 * ks), accG2a[1]);
            accG2a[2] = mfma_bf16(a2, *(const bf16x8*)(bI + (size_t)512 * KH + 32 * ks), accG2a[2]);
            bf16x8 bf = *(const bf16x8*)(bF + 32 * ks);
            accG2b[0] = mfma_bf16(al, bf, accG2b[0]);
            accG2b[1] = mfma_bf16(ar, bf, accG2b[1]);
        }
    }

    // ---- GEMM1: x-path (K=320, 10 k-steps) ----
    {
        const __bf16* aX = &Xs[lc * SX + koff];
        const __bf16* bX = wtx + (size_t)colw * KX + koff;
#pragma unroll
        for (int ks = 0; ks < KX / 32; ++ks) {
            bf16x8 a1 = *(const bf16x8*)(aX + 32 * ks);
#pragma unroll
            for (int t = 0; t < NG1; ++t)
                accG1[t] = mfma_bf16(a1, *(const bf16x8*)(bX + (size_t)(256 * t) * KX + 32 * ks), accG1[t]);
        }
    }

    // ---- epilogue ----
    // C/D layout: col = lane&15 (= lc), row = 4*q + reg. So this lane holds
    // nodes m = 4q+r for G1/G2a, and children rows 16*mt+4q+r for G2b.
    const int j = colw;                    // global output column
    const float bi = b_ioux[j] + b_iouh[j];
    const float bo = b_ioux[256 + j] + b_iouh[256 + j];
    const float bu = b_ioux[512 + j] + b_iouh[512 + j];

    float iv[4], ov[4], uv[4];
#pragma unroll
    for (int r = 0; r < 4; ++r) {
        float ai = accG1[0][r], ao = accG1[1][r], au = accG1[2][r];
        if constexpr (!LEAF) {
            ai += accG2a[0][r]; ao += accG2a[1][r]; au += accG2a[2][r];
        }
        iv[r] = sigmoidf_(ai + bi);
        ov[r] = sigmoidf_(ao + bo);
        uv[r] = tanhfast_(au + bu);
    }

    if constexpr (!LEAF) {
        const float bfx = b_fx[j], bfh = b_fh[j];
        float* S = &Scr[w][0];
        // 1) ship fx (pre-activation x-part of f) to the child lanes
#pragma unroll
        for (int r = 0; r < 4; ++r)
            S[(4 * q + r) * 17 + lc] = accG1[3][r] + bfx;
        __syncthreads();
        // 2) child lanes: f gates * child c, reduce sibling pairs (adjacent regs)
        float fcs[4];
#pragma unroll
        for (int mt = 0; mt < 2; ++mt) {
#pragma unroll
            for (int pr = 0; pr < 2; ++pr) {
                int p = 8 * mt + 2 * q + pr;           // parent index in tile
                float fxp = S[p * 17 + lc] + bfh;
                float f0 = sigmoidf_(accG2b[mt][2 * pr] + fxp);
                float f1 = sigmoidf_(accG2b[mt][2 * pr + 1] + fxp);
                float c0 = 0.f, c1 = 0.f;
                if (p < mcount) {
                    c0 = c[(size_t)(childbase + 2 * p) * MEM + j];
                    c1 = c[(size_t)(childbase + 2 * p + 1) * MEM + j];
                }
                fcs[2 * mt + pr] = f0 * c0 + f1 * c1;
            }
        }
        __syncthreads();
        // 3) ship fc_sum back to the parent lanes
#pragma unroll
        for (int mt = 0; mt < 2; ++mt)
#pragma unroll
            for (int pr = 0; pr < 2; ++pr)
                S[(8 * mt + 2 * q + pr) * 17 + lc] = fcs[2 * mt + pr];
        __syncthreads();
        // 4) final gates + store
#pragma unroll
        for (int r = 0; r < 4; ++r) {
            int m = 4 * q + r;
            float cn = iv[r] * uv[r] + S[m * 17 + lc];
            float hn = ov[r] * tanhfast_(cn);
            if (m < mcount) {
                c[(size_t)(node0 + m) * MEM + j] = cn;
                h[(size_t)(node0 + m) * MEM + j] = hn;
            }
        }
    } else {
#pragma unroll
        for (int r = 0; r < 4; ++r) {
            int m = 4 * q + r;
            float cn = iv[r] * uv[r];
            float hn = ov[r] * tanhfast_(cn);
            if (m < mcount) {
                c[(size_t)(node0 + m) * MEM + j] = cn;
                h[(size_t)(node0 + m) * MEM + j] = hn;
            }
        }
    }
}

extern "C" void kernel_launch(void* const* d_in, const int* in_sizes, int n_in,
                              void* d_out, int out_size, void* d_ws, size_t ws_size,
                              hipStream_t stream) {
    const float* inputs = (const float*)d_in[0];
    const float* W_ioux = (const float*)d_in[1];
    const float* b_ioux = (const float*)d_in[2];
    const float* W_iouh = (const float*)d_in[3];
    const float* b_iouh = (const float*)d_in[4];
    const float* W_fx   = (const float*)d_in[5];
    const float* b_fx   = (const float*)d_in[6];
    const float* W_fh   = (const float*)d_in[7];
    const float* b_fh   = (const float*)d_in[8];

    float* out = (float*)d_out;
    float* c = out;                                  // [N, MEM]
    float* h = out + (size_t)NNODES * MEM;           // [N, MEM]

    __bf16* wtx = (__bf16*)d_ws;                     // [1024][KX]
    __bf16* wth = wtx + WTX_ELEMS;                   // [1024][KH]

    {
        int total = WTX_ELEMS + WTH_ELEMS;           // 589824 elems (1.18 MB)
        hipLaunchKernelGGL(prep_weights, dim3((total + 255) / 256), dim3(256),
                           0, stream, W_ioux, W_fx, W_iouh, W_fh, (__bf16*)d_ws);
    }

    for (int d = DEPTH; d >= 0; --d) {
        int start = (1 << d) - 1;
        int sz = 1 << d;
        int blocks = (sz + 15) / 16;
        if (d == DEPTH) {
            hipLaunchKernelGGL((level_mfma<true>), dim3(blocks), dim3(1024), 0, stream,
                               inputs, wtx, wth, b_ioux, b_iouh, b_fx, b_fh,
                               c, h, start, sz);
        } else {
            hipLaunchKernelGGL((level_mfma<false>), dim3(blocks), dim3(1024), 0, stream,
                               inputs, wtx, wth, b_ioux, b_iouh, b_fx, b_fh,
                               c, h, start, sz);
        }
    }
}

// Round 3
// 590.044 us; speedup vs baseline: 4.9861x; 1.7824x over previous
//
#include <hip/hip_runtime.h>
#include <math.h>

#define IN_DIM 300
#define MEM 256
#define DEPTH 15
#define NNODES ((1 << (DEPTH + 1)) - 1)   // 65535
#define KX 320     // x-GEMM K (300 padded)
#define KH 256     // h-GEMM K
#define NKX 10     // KX/32
#define NKH 8      // KH/32
#define SX 328     // LDS row stride bf16 (656B = 41*16, phase-conflict-free)
#define SH 264     // LDS row stride bf16 (528B = 33*16)

typedef __attribute__((ext_vector_type(8))) __bf16 bf16x8;
typedef __attribute__((ext_vector_type(4))) float f32x4;

__device__ __forceinline__ float sigmoidf_(float x) { return 1.0f / (1.0f + __expf(-x)); }
__device__ __forceinline__ float tanhfast_(float x) {
    return 1.0f - 2.0f / (__expf(2.0f * x) + 1.0f);
}
__device__ __forceinline__ f32x4 mfma_bf16(bf16x8 a, bf16x8 b, f32x4 acc) {
    return __builtin_amdgcn_mfma_f32_16x16x32_bf16(a, b, acc, 0, 0, 0);
}

// Fragment-linear B layout: elem(cb, ks, lane, e) at ((cb*NK + ks)*64 + lane)*8 + e,
// holding W[col = cb*16 + (lane&15)][k = ks*32 + (lane>>4)*8 + e].
// A wave's B-fragment load for (cb, ks) is then 64 lanes x 16B CONTIGUOUS (1KB burst).
#define WTXF_ELEMS (64 * NKX * 512)   // 327680  (cols 0..767 = W_ioux, 768..1023 = W_fx)
#define WTHF_ELEMS (64 * NKH * 512)   // 262144  (cols 0..767 = W_iouh, 768..1023 = W_fh)

__global__ void prep_weights(const float* __restrict__ W_ioux, const float* __restrict__ W_fx,
                             const float* __restrict__ W_iouh, const float* __restrict__ W_fh,
                             __bf16* __restrict__ ws) {
    int idx = blockIdx.x * 256 + threadIdx.x;
    if (idx < WTXF_ELEMS) {
        int e = idx & 7, ln = (idx >> 3) & 63;
        int r = idx >> 9;             // 0..639
        int ks = r % NKX, cb = r / NKX;
        int col = cb * 16 + (ln & 15);
        int k = ks * 32 + (ln >> 4) * 8 + e;
        float v = 0.f;
        if (k < IN_DIM)
            v = (col < 768) ? W_ioux[col * IN_DIM + k] : W_fx[(col - 768) * IN_DIM + k];
        ws[idx] = (__bf16)v;
    } else if (idx < WTXF_ELEMS + WTHF_ELEMS) {
        int t = idx - WTXF_ELEMS;
        int e = t & 7, ln = (t >> 3) & 63;
        int r = t >> 9;               // 0..511
        int ks = r & 7, cb = r >> 3;
        int col = cb * 16 + (ln & 15);
        int k = ks * 32 + (ln >> 4) * 8 + e;
        float v = (col < 768) ? W_iouh[col * MEM + k] : W_fh[(col - 768) * MEM + k];
        ws[WTXF_ELEMS + t] = (__bf16)v;
    }
}

// One block = MT*16 nodes. 1024 threads = 16 waves. Wave w owns output cols
// [16w,16w+16) of all four gate groups (cb = g*16 + w). Children are staged
// de-interleaved (left rows 0..NT-1, right rows NT..2NT-1) so the f-gate
// GEMM's C rows index parents directly -> fully lane-local epilogue.
template <int MT, bool LEAF, int MINW>
__global__ __launch_bounds__(1024, MINW) void level_mfma(
    const float* __restrict__ x_in,
    const __bf16* __restrict__ wtx,   // fragment-linear, see above
    const __bf16* __restrict__ wth,
    const float* __restrict__ b_ioux, const float* __restrict__ b_iouh,
    const float* __restrict__ b_fx, const float* __restrict__ b_fh,
    float* __restrict__ c, float* __restrict__ h,
    int start, int levsize)
{
    constexpr int NT = MT * 16;
    const int tid = threadIdx.x;
    const int w = tid >> 6, l = tid & 63, lc = l & 15, q = l >> 4;
    const int tile0 = blockIdx.x * NT;
    const int node0 = start + tile0;
    const int mcount = min(NT, levsize - tile0);
    const int childbase = 2 * node0 + 1;

    __shared__ __align__(16) __bf16 Xs[NT * SX];                   // MT=4: 41.0 KB
    __shared__ __align__(16) __bf16 Hlr[LEAF ? 8 : 2 * NT * SH];   // MT=4: 66.0 KB
    __shared__ __align__(16) __bf16 Hsum[LEAF ? 8 : NT * SH];      // MT=4: 33.0 KB

    // ---- stage X: one 16B LDS store per thread-iter (no bank conflicts) ----
    for (int t = tid; t < NT * (KX / 8); t += 1024) {
        int m = t / (KX / 8), kc = t - m * (KX / 8), k = kc * 8;
        float4 v0 = {0.f, 0.f, 0.f, 0.f}, v1 = {0.f, 0.f, 0.f, 0.f};
        if (m < mcount) {
            const float* row = x_in + (size_t)(node0 + m) * IN_DIM;
            if (k + 8 <= IN_DIM) { v0 = *(const float4*)(row + k); v1 = *(const float4*)(row + k + 4); }
            else if (k == 296)   { v0 = *(const float4*)(row + k); }   // 296..299 valid
        }
        bf16x8 pk;
        pk[0] = (__bf16)v0.x; pk[1] = (__bf16)v0.y; pk[2] = (__bf16)v0.z; pk[3] = (__bf16)v0.w;
        pk[4] = (__bf16)v1.x; pk[5] = (__bf16)v1.y; pk[6] = (__bf16)v1.z; pk[7] = (__bf16)v1.w;
        *(bf16x8*)&Xs[m * SX + k] = pk;
    }
    // ---- stage children h (de-interleaved) + hsum ----
    if constexpr (!LEAF) {
        for (int t = tid; t < NT * (KH / 8); t += 1024) {
            int m = t >> 5, kc = t & 31, k = kc * 8;
            float4 l0 = {0.f,0.f,0.f,0.f}, l1 = l0, r0 = l0, r1 = l0;
            if (m < mcount) {
                const float4* lp = (const float4*)(h + (size_t)(childbase + 2 * m) * MEM + k);
                const float4* rp = (const float4*)(h + (size_t)(childbase + 2 * m + 1) * MEM + k);
                l0 = lp[0]; l1 = lp[1]; r0 = rp[0]; r1 = rp[1];
            }
            bf16x8 pl, pr, ps;
            pl[0]=(__bf16)l0.x; pl[1]=(__bf16)l0.y; pl[2]=(__bf16)l0.z; pl[3]=(__bf16)l0.w;
            pl[4]=(__bf16)l1.x; pl[5]=(__bf16)l1.y; pl[6]=(__bf16)l1.z; pl[7]=(__bf16)l1.w;
            pr[0]=(__bf16)r0.x; pr[1]=(__bf16)r0.y; pr[2]=(__bf16)r0.z; pr[3]=(__bf16)r0.w;
            pr[4]=(__bf16)r1.x; pr[5]=(__bf16)r1.y; pr[6]=(__bf16)r1.z; pr[7]=(__bf16)r1.w;
            ps[0]=(__bf16)(l0.x+r0.x); ps[1]=(__bf16)(l0.y+r0.y);
            ps[2]=(__bf16)(l0.z+r0.z); ps[3]=(__bf16)(l0.w+r0.w);
            ps[4]=(__bf16)(l1.x+r1.x); ps[5]=(__bf16)(l1.y+r1.y);
            ps[6]=(__bf16)(l1.z+r1.z); ps[7]=(__bf16)(l1.w+r1.w);
            *(bf16x8*)&Hlr[m * SH + k] = pl;
            *(bf16x8*)&Hlr[(NT + m) * SH + k] = pr;
            *(bf16x8*)&Hsum[m * SH + k] = ps;
        }
    }
    __syncthreads();

    constexpr int NG1 = LEAF ? 3 : 4;
    const f32x4 z4 = {0.f, 0.f, 0.f, 0.f};
    f32x4 acc1[NG1][MT];
    f32x4 acc2a[3][MT], accL[MT], accR[MT];
#pragma unroll
    for (int g = 0; g < NG1; ++g)
#pragma unroll
        for (int mt = 0; mt < MT; ++mt) acc1[g][mt] = z4;

    // ---- h-path GEMMs ----
    if constexpr (!LEAF) {
#pragma unroll
        for (int mt = 0; mt < MT; ++mt) {
            acc2a[0][mt] = z4; acc2a[1][mt] = z4; acc2a[2][mt] = z4;
            accL[mt] = z4; accR[mt] = z4;
        }
        const __bf16* b0 = wth + ((size_t)(w)      * NKH) * 512 + l * 8;
        const __bf16* b1 = wth + ((size_t)(16 + w) * NKH) * 512 + l * 8;
        const __bf16* b2 = wth + ((size_t)(32 + w) * NKH) * 512 + l * 8;
        const __bf16* bF = wth + ((size_t)(48 + w) * NKH) * 512 + l * 8;
        for (int ks = 0; ks < NKH; ++ks) {
            bf16x8 vb0 = *(const bf16x8*)(b0 + ks * 512);
            bf16x8 vb1 = *(const bf16x8*)(b1 + ks * 512);
            bf16x8 vb2 = *(const bf16x8*)(b2 + ks * 512);
            bf16x8 vbf = *(const bf16x8*)(bF + ks * 512);
            const int ko = ks * 32 + q * 8;
#pragma unroll
            for (int mt = 0; mt < MT; ++mt) {
                bf16x8 as = *(const bf16x8*)&Hsum[(mt * 16 + lc) * SH + ko];
                bf16x8 al = *(const bf16x8*)&Hlr[(mt * 16 + lc) * SH + ko];
                bf16x8 ar = *(const bf16x8*)&Hlr[(NT + mt * 16 + lc) * SH + ko];
                acc2a[0][mt] = mfma_bf16(as, vb0, acc2a[0][mt]);
                acc2a[1][mt] = mfma_bf16(as, vb1, acc2a[1][mt]);
                acc2a[2][mt] = mfma_bf16(as, vb2, acc2a[2][mt]);
                accL[mt] = mfma_bf16(al, vbf, accL[mt]);
                accR[mt] = mfma_bf16(ar, vbf, accR[mt]);
            }
        }
    }

    // ---- x-path GEMM ----
    {
        const __bf16* bx0 = wtx + ((size_t)(w)      * NKX) * 512 + l * 8;
        const __bf16* bx1 = wtx + ((size_t)(16 + w) * NKX) * 512 + l * 8;
        const __bf16* bx2 = wtx + ((size_t)(32 + w) * NKX) * 512 + l * 8;
        const __bf16* bx3 = wtx + ((size_t)(48 + w) * NKX) * 512 + l * 8;
        for (int ks = 0; ks < NKX; ++ks) {
            bf16x8 vb0 = *(const bf16x8*)(bx0 + ks * 512);
            bf16x8 vb1 = *(const bf16x8*)(bx1 + ks * 512);
            bf16x8 vb2 = *(const bf16x8*)(bx2 + ks * 512);
            bf16x8 vb3;
            if constexpr (!LEAF) vb3 = *(const bf16x8*)(bx3 + ks * 512);
            const int ko = ks * 32 + q * 8;
#pragma unroll
            for (int mt = 0; mt < MT; ++mt) {
                bf16x8 ax = *(const bf16x8*)&Xs[(mt * 16 + lc) * SX + ko];
                acc1[0][mt] = mfma_bf16(ax, vb0, acc1[0][mt]);
                acc1[1][mt] = mfma_bf16(ax, vb1, acc1[1][mt]);
                acc1[2][mt] = mfma_bf16(ax, vb2, acc1[2][mt]);
                if constexpr (!LEAF) acc1[3][mt] = mfma_bf16(ax, vb3, acc1[3][mt]);
            }
        }
    }

    // ---- lane-local epilogue (C/D: col = lane&15, row = 4*(lane>>4) + reg) ----
    const int jj = w * 16 + lc;
    const float bi = b_ioux[jj]       + b_iouh[jj];
    const float bo = b_ioux[256 + jj] + b_iouh[256 + jj];
    const float bu = b_ioux[512 + jj] + b_iouh[512 + jj];
    float bff = 0.f;
    if constexpr (!LEAF) bff = b_fx[jj] + b_fh[jj];

#pragma unroll
    for (int mt = 0; mt < MT; ++mt) {
#pragma unroll
        for (int r = 0; r < 4; ++r) {
            const int n = mt * 16 + q * 4 + r;
            float ai = acc1[0][mt][r], ao = acc1[1][mt][r], au = acc1[2][mt][r];
            if constexpr (!LEAF) {
                ai += acc2a[0][mt][r]; ao += acc2a[1][mt][r]; au += acc2a[2][mt][r];
            }
            const float iv = sigmoidf_(ai + bi);
            const float ov = sigmoidf_(ao + bo);
            const float uv = tanhfast_(au + bu);
            float cn;
            if constexpr (!LEAF) {
                const float fxv = acc1[3][mt][r] + bff;
                const float fl = sigmoidf_(accL[mt][r] + fxv);
                const float fr = sigmoidf_(accR[mt][r] + fxv);
                float cl = 0.f, cr = 0.f;
                if (n < mcount) {
                    cl = c[(size_t)(childbase + 2 * n) * MEM + jj];
                    cr = c[(size_t)(childbase + 2 * n + 1) * MEM + jj];
                }
                cn = iv * uv + fl * cl + fr * cr;
            } else {
                cn = iv * uv;
            }
            const float hn = ov * tanhfast_(cn);
            if (n < mcount) {
                c[(size_t)(node0 + n) * MEM + jj] = cn;
                h[(size_t)(node0 + n) * MEM + jj] = hn;
            }
        }
    }
}

extern "C" void kernel_launch(void* const* d_in, const int* in_sizes, int n_in,
                              void* d_out, int out_size, void* d_ws, size_t ws_size,
                              hipStream_t stream) {
    const float* inputs = (const float*)d_in[0];
    const float* W_ioux = (const float*)d_in[1];
    const float* b_ioux = (const float*)d_in[2];
    const float* W_iouh = (const float*)d_in[3];
    const float* b_iouh = (const float*)d_in[4];
    const float* W_fx   = (const float*)d_in[5];
    const float* b_fx   = (const float*)d_in[6];
    const float* W_fh   = (const float*)d_in[7];
    const float* b_fh   = (const float*)d_in[8];

    float* out = (float*)d_out;
    float* c = out;
    float* h = out + (size_t)NNODES * MEM;

    __bf16* wtx = (__bf16*)d_ws;
    __bf16* wth = wtx + WTXF_ELEMS;

    {
        int total = WTXF_ELEMS + WTHF_ELEMS;
        hipLaunchKernelGGL(prep_weights, dim3((total + 255) / 256), dim3(256),
                           0, stream, W_ioux, W_fx, W_iouh, W_fh, (__bf16*)d_ws);
    }

    // d = 15 (leaves), d = 14, d = 13: 64-node blocks (B-stream amortized 4x)
    hipLaunchKernelGGL((level_mfma<4, true, 2>), dim3(512), dim3(1024), 0, stream,
                       inputs, wtx, wth, b_ioux, b_iouh, b_fx, b_fh, c, h,
                       (1 << 15) - 1, 1 << 15);
    hipLaunchKernelGGL((level_mfma<4, false, 2>), dim3(256), dim3(1024), 0, stream,
                       inputs, wtx, wth, b_ioux, b_iouh, b_fx, b_fh, c, h,
                       (1 << 14) - 1, 1 << 14);
    hipLaunchKernelGGL((level_mfma<4, false, 2>), dim3(128), dim3(1024), 0, stream,
                       inputs, wtx, wth, b_ioux, b_iouh, b_fx, b_fh, c, h,
                       (1 << 13) - 1, 1 << 13);
    // d <= 12: 16-node blocks
    for (int d = 12; d >= 0; --d) {
        int start = (1 << d) - 1;
        int sz = 1 << d;
        int blocks = (sz + 15) / 16;
        hipLaunchKernelGGL((level_mfma<1, false, 4>), dim3(blocks), dim3(1024), 0, stream,
                           inputs, wtx, wth, b_ioux, b_iouh, b_fx, b_fh, c, h,
                           start, sz);
    }
}